// Round 1
// baseline (143914.355 us; speedup 1.0000x reference)
//
#include <hip/hip_runtime.h>
#include <math.h>

#define Bn 256
#define Sn 1024
#define Ln 32
#define En 128
#define Hn 256
#define Mn 10
#define OUTn 121
#define K1n 387   // 128 wv + 3 x + 256 h1
#define K2n 640   // 256 hA + 128 wv + 256 hprev
#define LD1n 388  // LDS leading dim (K1+1): %32==4 -> <=2-way bank alias (free)
#define LD2n 641  // %32==1 -> conflict-free

__device__ __forceinline__ float sigmoidf_(float x) {
    return 1.0f / (1.0f + __expf(-x));
}
__device__ __forceinline__ float tanhf_(float x) {
    // 1 - 2/(e^{2x}+1); saturates correctly at +-inf
    return 1.0f - 2.0f / (__expf(2.0f * x) + 1.0f);
}
__device__ __forceinline__ float softplus_(float x) {
    return (x > 20.0f) ? x : log1pf(__expf(x));
}

// Pack weights: WT[k][h][g] = W(row=g*256+h, col=k), ih-part then hh-part.
__global__ __launch_bounds__(256) void pack_kernel(
    const float* __restrict__ Wih1, const float* __restrict__ Whh1,
    const float* __restrict__ Wih2, const float* __restrict__ Whh2,
    const float* __restrict__ Wih3, const float* __restrict__ Whh3,
    float* __restrict__ WT1, float* __restrict__ WT2, float* __restrict__ WT3)
{
    int idx = blockIdx.x * 256 + threadIdx.x;
    if (idx >= K2n * 1024) return;
    int g = idx & 3;
    int h = (idx >> 2) & 255;
    int k = idx >> 10;
    int row = g * 256 + h;
    if (idx < K1n * 1024)
        WT1[idx] = (k < 131) ? Wih1[row * 131 + k] : Whh1[row * 256 + (k - 131)];
    WT2[idx] = (k < 384) ? Wih2[row * 384 + k] : Whh2[row * 256 + (k - 384)];
    WT3[idx] = (k < 384) ? Wih3[row * 384 + k] : Whh3[row * 256 + (k - 384)];
}

// One LSTM layer: gates GEMM (B x 4H, K=KTOT) + cell update.
// Grid: (16 batch-tiles, 16 h-tiles), 256 threads = 16 h x 16 b.
// TRAJMODE (layer 1): x = [wv(128) | traj[b,t,:](3) | h1prev(256)]
// else (layers 2/3):  x = [hA(256)  | wv(128)        | hprev(256)]
template <bool TRAJMODE, int KTOT, int LDX>
__global__ __launch_bounds__(256, 1) void gates_kernel(
    const float* __restrict__ WT, const float* __restrict__ bias,
    const float* __restrict__ s0, const float* __restrict__ s1,
    const float* __restrict__ traj, int t,
    const float* __restrict__ hprev, float* __restrict__ hnext,
    float* __restrict__ cstate)
{
    __shared__ float ldsX[16 * LDX];
    const int tid = threadIdx.x;
    const int bt = blockIdx.x, ht = blockIdx.y;

    for (int idx = tid; idx < 16 * KTOT; idx += 256) {
        int bl = idx / KTOT;
        int k = idx - bl * KTOT;
        int b = bt * 16 + bl;
        float v;
        if (TRAJMODE) {
            if (k < 128)      v = s0[b * 128 + k];
            else if (k < 131) v = traj[((size_t)b * Sn + t) * 3 + (k - 128)];
            else              v = hprev[b * 256 + (k - 131)];
        } else {
            if (k < 256)      v = s0[b * 256 + k];
            else if (k < 384) v = s1[b * 128 + (k - 256)];
            else              v = hprev[b * 256 + (k - 384)];
        }
        ldsX[bl * LDX + k] = v;
    }
    __syncthreads();

    const int hl = tid & 15, bl = tid >> 4;
    const int hg = ht * 16 + hl;     // global hidden unit
    const int b  = bt * 16 + bl;     // global batch
    const float* wp = WT + hg * 4;
    const float* xp = ldsX + bl * LDX;

    float ai = 0.f, af = 0.f, ag = 0.f, ao = 0.f;
#pragma unroll 8
    for (int k = 0; k < KTOT; ++k) {
        const float4 w = *(const float4*)(wp + (k << 10));
        const float x = xp[k];
        ai = fmaf(w.x, x, ai);
        af = fmaf(w.y, x, af);
        ag = fmaf(w.z, x, ag);
        ao = fmaf(w.w, x, ao);
    }
    float gi = sigmoidf_(ai + bias[hg]);
    float gf = sigmoidf_(af + bias[256 + hg]);
    float gg = tanhf_(ag + bias[512 + hg]);
    float go = sigmoidf_(ao + bias[768 + hg]);
    float c  = cstate[b * 256 + hg];
    float cn = fmaf(gf, c, gi * gg);
    cstate[b * 256 + hg] = cn;
    hnext[b * 256 + hg]  = go * tanhf_(cn);
}

// Attention + wv update for step t; also emits out(t-1) (off critical path).
// One workgroup per batch element.
__global__ __launch_bounds__(256, 1) void att_kernel(
    const float* __restrict__ Watt, const float* __restrict__ batt,
    const float* __restrict__ Wout, const float* __restrict__ bout,
    const float* __restrict__ emb, const int* __restrict__ words,
    const int* __restrict__ wlen, const float* __restrict__ traj, int t,
    const float* __restrict__ h1c, const float* __restrict__ h3p,
    float* __restrict__ wv, float* __restrict__ kappa,
    float* __restrict__ out, int out_t, int only_out)
{
    __shared__ float attin[K1n];
    __shared__ float h3s[Hn];
    __shared__ float red[240];
    __shared__ float pv[30];
    __shared__ float s_alpha[Mn], s_rbeta[Mn], s_kap[Mn];
    __shared__ float phi[Ln + 1];
    __shared__ int wint[Ln];
    __shared__ int slen;
    const int tid = threadIdx.x;
    const int b = blockIdx.x;

    if (!only_out) {
        for (int k = tid; k < K1n; k += 256)
            attin[k] = (k < 128) ? wv[b * 128 + k]
                     : ((k < 131) ? traj[((size_t)b * Sn + t) * 3 + (k - 128)]
                                  : h1c[b * 256 + (k - 131)]);
        if (tid < Ln) wint[tid] = words[b * Ln + tid];
        if (tid == 0) slen = wlen[b];
    }
    if (out_t >= 0) {
        for (int k = tid; k < Hn; k += 256) h3s[k] = h3p[b * 256 + k];
    }
    __syncthreads();

    if (!only_out) {
        // p = attin @ Watt^T + batt  (30 rows, 8 lanes each)
        if (tid < 240) {
            int m = tid >> 3, c = tid & 7;
            float part = 0.f;
            for (int k = c; k < K1n; k += 8)
                part = fmaf(attin[k], Watt[m * K1n + k], part);
            red[tid] = part;
        }
        __syncthreads();
        if (tid < 30) {
            float p = batt[tid];
#pragma unroll
            for (int j = 0; j < 8; ++j) p += red[tid * 8 + j];
            pv[tid] = p;
        }
        __syncthreads();
        if (tid < Mn) {
            float a  = softplus_(pv[tid]);
            float bb = fmaxf(softplus_(pv[10 + tid]), 0.01f);
            float kp = kappa[b * Mn + tid] + softplus_(pv[20 + tid]) * (1.0f / 25.0f);
            s_alpha[tid] = a;
            s_rbeta[tid] = 1.0f / bb;
            s_kap[tid]   = kp;
            kappa[b * Mn + tid] = kp;   // state update
        }
        __syncthreads();
        if (tid < Ln) {
            float ph = 0.f;
            if (tid < slen) {
#pragma unroll
                for (int m = 0; m < Mn; ++m) {
                    float d = s_kap[m] - (float)tid;
                    ph = fmaf(s_alpha[m], __expf(-d * d * s_rbeta[m]), ph);
                }
            }
            phi[tid] = ph;
        }
        __syncthreads();
        if (tid == 0) {
            float s = 0.f;
            for (int l = 0; l < Ln; ++l) s += phi[l];
            phi[Ln] = 1.0f / (s + 1e-8f);
        }
        __syncthreads();
        if (tid < En) {
            float inv = phi[Ln];
            float acc = 0.f;
            for (int l = 0; l < Ln; ++l)
                acc = fmaf(phi[l], emb[wint[l] * En + tid], acc);
            wv[b * En + tid] = acc * inv;
        }
    }
    if (out_t >= 0 && tid < OUTn) {
        float acc = bout[tid];
        for (int k = 0; k < Hn; ++k)
            acc = fmaf(h3s[k], Wout[tid * Hn + k], acc);
        out[((size_t)b * Sn + out_t) * OUTn + tid] = acc;
    }
}

extern "C" void kernel_launch(void* const* d_in, const int* in_sizes, int n_in,
                              void* d_out, int out_size, void* d_ws, size_t ws_size,
                              hipStream_t stream)
{
    const float* traj = (const float*)d_in[0];
    const int*   words = (const int*)d_in[1];
    const int*   wlen  = (const int*)d_in[2];
    const float* emb   = (const float*)d_in[3];
    const float* Wih1  = (const float*)d_in[4];
    const float* Whh1  = (const float*)d_in[5];
    const float* b1    = (const float*)d_in[6];
    const float* Wih2  = (const float*)d_in[7];
    const float* Whh2  = (const float*)d_in[8];
    const float* b2    = (const float*)d_in[9];
    const float* Wih3  = (const float*)d_in[10];
    const float* Whh3  = (const float*)d_in[11];
    const float* b3    = (const float*)d_in[12];
    const float* Watt  = (const float*)d_in[13];
    const float* batt  = (const float*)d_in[14];
    const float* Wout  = (const float*)d_in[15];
    const float* bout  = (const float*)d_in[16];
    float* out = (float*)d_out;

    float* ws = (float*)d_ws;
    float* WT1 = ws;
    float* WT2 = WT1 + (size_t)K1n * 1024;
    float* WT3 = WT2 + (size_t)K2n * 1024;
    float* p = WT3 + (size_t)K2n * 1024;
    float* stbase = p;
    float* h1b[2]; float* h2b[2]; float* h3b[2];
    h1b[0] = p; p += Bn * Hn; h1b[1] = p; p += Bn * Hn;
    h2b[0] = p; p += Bn * Hn; h2b[1] = p; p += Bn * Hn;
    h3b[0] = p; p += Bn * Hn; h3b[1] = p; p += Bn * Hn;
    float* c1 = p; p += Bn * Hn;
    float* c2 = p; p += Bn * Hn;
    float* c3 = p; p += Bn * Hn;
    float* wvb = p; p += Bn * En;
    float* kap = p; p += Bn * Mn;
    size_t stbytes = (size_t)(p - stbase) * sizeof(float);

    hipMemsetAsync(stbase, 0, stbytes, stream);
    pack_kernel<<<(K2n * 1024 + 255) / 256, 256, 0, stream>>>(
        Wih1, Whh1, Wih2, Whh2, Wih3, Whh3, WT1, WT2, WT3);

    dim3 ggrid(16, 16);
    for (int t = 0; t < Sn; ++t) {
        float* h1p = h1b[t & 1];       float* h1c = h1b[(t + 1) & 1];
        float* h2p = h2b[t & 1];       float* h2c = h2b[(t + 1) & 1];
        float* h3p = h3b[t & 1];       float* h3c = h3b[(t + 1) & 1];

        // LSTM 1: x = [wv_prev, x_t], recur h1p
        gates_kernel<true, K1n, LD1n><<<ggrid, 256, 0, stream>>>(
            WT1, b1, wvb, nullptr, traj, t, h1p, h1c, c1);
        // attention (reads wv_prev + h1c, writes wv, kappa) + out(t-1)
        att_kernel<<<Bn, 256, 0, stream>>>(
            Watt, batt, Wout, bout, emb, words, wlen, traj, t,
            h1c, h3p, wvb, kap, out, t - 1, 0);
        // LSTM 2: x = [h1c, wv], recur h2p
        gates_kernel<false, K2n, LD2n><<<ggrid, 256, 0, stream>>>(
            WT2, b2, h1c, wvb, traj, t, h2p, h2c, c2);
        // LSTM 3: x = [h2c, wv], recur h3p
        gates_kernel<false, K2n, LD2n><<<ggrid, 256, 0, stream>>>(
            WT3, b3, h2c, wvb, traj, t, h3p, h3c, c3);
    }
    // final output row: out(1023) from h3b[(1023+1)&1] = h3b[0]
    att_kernel<<<Bn, 256, 0, stream>>>(
        Watt, batt, Wout, bout, emb, words, wlen, traj, 0,
        h1b[0], h3b[0], wvb, kap, out, Sn - 1, 1);
}